// Round 19
// baseline (20.288 us; speedup 1.0000x reference)
//
#include <hip/hip_runtime.h>

#define KMAX 64
#define BB 4
#define LL 4096
#define DD 64
#define TOK (BB * LL)   // 16384 tokens per side
#define QPW 4           // queries per wave
#define WPB 16          // waves per block (1024 threads)
#define QPB (QPW * WPB) // 64 queries per block

typedef unsigned long long u64;

// Phase 1 (VERBATIM R14/R18, bitwise-verified absmax 0.0 since R1): one
// thread per token-side; strictly sequential d=0..63 fmaf accumulation —
// DO NOT tree-reduce (floor() at bucket edges is order-sensitive).
__global__ __launch_bounds__(64) void codes_kernel(
        const float* __restrict__ q,
        const float* __restrict__ k,
        const float* __restrict__ W,
        int* __restrict__ codes /* [0,TOK)=qcodes, [TOK,2*TOK)=kcodes */) {
    __shared__ float sW[DD * 4];
    int lane = threadIdx.x;
    #pragma unroll
    for (int i = 0; i < 4; ++i) sW[i * 64 + lane] = W[i * 64 + lane];
    __syncthreads();

    int u = blockIdx.x * 64 + lane;          // grid covers 2*TOK exactly
    const float* src = (u < TOK) ? q : k;
    int t = u & (TOK - 1);

    const float4* xp = (const float4*)(src + (size_t)t * DD);
    float4 x[16];
    #pragma unroll
    for (int i = 0; i < 16; ++i) x[i] = xp[i];

    float p0 = 0.f, p1 = 0.f, p2 = 0.f, p3 = 0.f;
    const float4* wrow = (const float4*)sW;
    #pragma unroll
    for (int d = 0; d < DD; ++d) {
        float xv = ((const float*)x)[d];
        float b = (xv > 0.f) ? 1.0f : 0.0f;      // binary_quantize
        float4 w = wrow[d];
        p0 = fmaf(b, w.x, p0);
        p1 = fmaf(b, w.y, p1);
        p2 = fmaf(b, w.z, p2);
        p3 = fmaf(b, w.w, p3);
    }
    int h0 = ((int)floorf(p0 * 0.5f)) & 31;      // floor(p/2) mod 32
    int h1 = ((int)floorf(p1 * 0.5f)) & 31;
    int h2 = ((int)floorf(p2 * 0.5f)) & 31;
    int h3 = ((int)floorf(p3 * 0.5f)) & 31;
    codes[u] = h0 | (h1 << 5) | (h2 << 10) | (h3 << 15);
}

// Phase 2: single-variable change vs R18 — 256 blocks x 16 waves (was
// 512 x 8). One 16 KB staging now serves 64 queries: global staging traffic
// 8 MB -> 4 MB; exactly 1 block/CU (flattest dispatch). Same 4096 waves x
// QPW=4. Scan body VERBATIM from R11/R14/R18 (absmax 0.0): whole-batch
// register prefetch from LDS; combined 1-ballot reject; lane-major ordered
// write (j = g*256+lane*4+e; before = sum of 4 ballots & lowmask;
// within-lane order via sequential pos++); -1 tail fill.
__global__ __launch_bounds__(1024) void find_kernel(
        const int* __restrict__ qcodes,
        const int* __restrict__ kcodes,
        int* __restrict__ out) {
    __shared__ int skc[LL];                  // 16 KB
    int tid = threadIdx.x;                   // 0..1023
    int blk = blockIdx.x;                    // 256 blocks
    int b = blk >> 6;                        // 64 blocks per batch

    // stage batch k-codes: 1024 threads x 1 int4 = 16 KB, coalesced
    const int4* src = (const int4*)(kcodes + b * LL);
    ((int4*)skc)[tid] = src[tid];
    __syncthreads();

    int wave = tid >> 6, lane = tid & 63;
    int qbase = blk * QPB + wave * QPW;      // 4 queries, never crosses a batch
    const int* qp = qcodes + qbase;
    int* outb = out + (size_t)qbase * KMAX;
    u64 lowmask = (1ull << lane) - 1ull;

    // whole-batch register prefetch from LDS (R14)
    const int4* skc4 = (const int4*)skc;
    int4 kv[16];
    #pragma unroll
    for (int g = 0; g < 16; ++g) kv[g] = skc4[g * 64 + lane];

    int qc[QPW], cnt[QPW];
    #pragma unroll
    for (int i = 0; i < QPW; ++i) { qc[i] = qp[i]; cnt[i] = 0; }

    #pragma unroll
    for (int g = 0; g < 16; ++g) {                 // 16 groups of 256 j
        bool a0 = (kv[g].x == qc[0]) | (kv[g].y == qc[0]) | (kv[g].z == qc[0]) | (kv[g].w == qc[0]);
        bool a1 = (kv[g].x == qc[1]) | (kv[g].y == qc[1]) | (kv[g].z == qc[1]) | (kv[g].w == qc[1]);
        bool a2 = (kv[g].x == qc[2]) | (kv[g].y == qc[2]) | (kv[g].z == qc[2]) | (kv[g].w == qc[2]);
        bool a3 = (kv[g].x == qc[3]) | (kv[g].y == qc[3]) | (kv[g].z == qc[3]) | (kv[g].w == qc[3]);
        if (__ballot(a0 | a1 | a2 | a3) == 0) continue;    // usual case
        int j0 = g * 256 + lane * 4;
        #pragma unroll
        for (int i = 0; i < QPW; ++i) {            // full unroll: no runtime idx
            if (cnt[i] >= KMAX) continue;          // wave-uniform
            bool m0 = (kv[g].x == qc[i]), m1 = (kv[g].y == qc[i]);
            bool m2 = (kv[g].z == qc[i]), m3 = (kv[g].w == qc[i]);
            if (__ballot(m0 | m1 | m2 | m3) == 0) continue;
            u64 b0 = __ballot(m0), b1 = __ballot(m1);
            u64 b2 = __ballot(m2), b3 = __ballot(m3);
            int before = __popcll(b0 & lowmask) + __popcll(b1 & lowmask)
                       + __popcll(b2 & lowmask) + __popcll(b3 & lowmask);
            int pos = cnt[i] + before;
            int* op = outb + i * KMAX;
            if (m0) { if (pos < KMAX) op[pos] = j0;     ++pos; }
            if (m1) { if (pos < KMAX) op[pos] = j0 + 1; ++pos; }
            if (m2) { if (pos < KMAX) op[pos] = j0 + 2; ++pos; }
            if (m3) { if (pos < KMAX) op[pos] = j0 + 3; ++pos; }
            cnt[i] += __popcll(b0) + __popcll(b1) + __popcll(b2) + __popcll(b3);
        }
    }
    #pragma unroll
    for (int i = 0; i < QPW; ++i) {                // -1 tail fill, coalesced
        int p = cnt[i] + lane;
        if (p < KMAX) outb[i * KMAX + p] = -1;
    }
}

extern "C" void kernel_launch(void* const* d_in, const int* in_sizes, int n_in,
                              void* d_out, int out_size, void* d_ws, size_t ws_size,
                              hipStream_t stream) {
    const float* q = (const float*)d_in[0];
    const float* k = (const float*)d_in[1];
    const float* W = (const float*)d_in[2];
    int* out = (int*)d_out;
    int* codes = (int*)d_ws;                 // [2*TOK] ints (128 KB)
    int* qcodes = codes;
    int* kcodes = codes + TOK;

    codes_kernel<<<(2 * TOK) / 64, 64, 0, stream>>>(q, k, W, codes);

    find_kernel<<<TOK / QPB, 1024, 0, stream>>>(qcodes, kcodes, out);
}

// Round 20
// 19.761 us; speedup vs baseline: 1.0267x; 1.0267x over previous
//
#include <hip/hip_runtime.h>

#define KMAX 64
#define BB 4
#define LL 4096
#define DD 64
#define TOK (BB * LL)   // 16384 tokens per side
#define QPW 4           // queries per wave
#define WPB 8           // waves per block (512 threads)
#define QPB (QPW * WPB) // 32 queries per block

typedef unsigned long long u64;

// Phase 1 (VERBATIM, bitwise-verified absmax 0.0 since R1): one thread
// per token-side; strictly sequential d=0..63 fmaf accumulation — DO NOT
// tree-reduce (floor() at bucket edges is order-sensitive). 512 blocks x 64.
__global__ __launch_bounds__(64) void codes_kernel(
        const float* __restrict__ q,
        const float* __restrict__ k,
        const float* __restrict__ W,
        int* __restrict__ codes /* [0,TOK)=qcodes, [TOK,2*TOK)=kcodes */) {
    __shared__ float sW[DD * 4];
    int lane = threadIdx.x;
    #pragma unroll
    for (int i = 0; i < 4; ++i) sW[i * 64 + lane] = W[i * 64 + lane];
    __syncthreads();

    int u = blockIdx.x * 64 + lane;          // grid covers 2*TOK exactly
    const float* src = (u < TOK) ? q : k;
    int t = u & (TOK - 1);

    const float4* xp = (const float4*)(src + (size_t)t * DD);
    float4 x[16];
    #pragma unroll
    for (int i = 0; i < 16; ++i) x[i] = xp[i];

    float p0 = 0.f, p1 = 0.f, p2 = 0.f, p3 = 0.f;
    const float4* wrow = (const float4*)sW;
    #pragma unroll
    for (int d = 0; d < DD; ++d) {
        float xv = ((const float*)x)[d];
        float b = (xv > 0.f) ? 1.0f : 0.0f;      // binary_quantize
        float4 w = wrow[d];
        p0 = fmaf(b, w.x, p0);
        p1 = fmaf(b, w.y, p1);
        p2 = fmaf(b, w.z, p2);
        p3 = fmaf(b, w.w, p3);
    }
    int h0 = ((int)floorf(p0 * 0.5f)) & 31;      // floor(p/2) mod 32
    int h1 = ((int)floorf(p1 * 0.5f)) & 31;
    int h2 = ((int)floorf(p2 * 0.5f)) & 31;
    int h3 = ((int)floorf(p3 * 0.5f)) & 31;
    codes[u] = h0 | (h1 << 5) | (h2 << 10) | (h3 << 15);
}

// Phase 2 (VERBATIM R18, best measured 19.88 us): 512 blocks x 8 waves;
// 16 KB k-code staging shared by 32 queries (staging traffic 8 MB); 4096
// waves x QPW=4. Scan body verified absmax 0.0 across six rounds:
// whole-batch register prefetch from LDS; combined 1-ballot reject;
// lane-major ordered write (j = g*256+lane*4+e; before = sum of 4 ballots &
// lowmask; within-lane order via sequential pos++); -1 tail fill.
__global__ __launch_bounds__(512) void find_kernel(
        const int* __restrict__ qcodes,
        const int* __restrict__ kcodes,
        int* __restrict__ out) {
    __shared__ int skc[LL];                  // 16 KB
    int tid = threadIdx.x;                   // 0..511
    int blk = blockIdx.x;                    // 512 blocks
    int b = blk >> 7;                        // 128 blocks per batch

    // stage batch k-codes: 512 threads x 2 int4 = 16 KB, coalesced
    const int4* src = (const int4*)(kcodes + b * LL);
    int4* dst = (int4*)skc;
    #pragma unroll
    for (int i = 0; i < 2; ++i) dst[tid + i * 512] = src[tid + i * 512];
    __syncthreads();

    int wave = tid >> 6, lane = tid & 63;
    int qbase = blk * QPB + wave * QPW;      // 4 queries, never crosses a batch
    const int* qp = qcodes + qbase;
    int* outb = out + (size_t)qbase * KMAX;
    u64 lowmask = (1ull << lane) - 1ull;

    // whole-batch register prefetch from LDS (R14)
    const int4* skc4 = (const int4*)skc;
    int4 kv[16];
    #pragma unroll
    for (int g = 0; g < 16; ++g) kv[g] = skc4[g * 64 + lane];

    int qc[QPW], cnt[QPW];
    #pragma unroll
    for (int i = 0; i < QPW; ++i) { qc[i] = qp[i]; cnt[i] = 0; }

    #pragma unroll
    for (int g = 0; g < 16; ++g) {                 // 16 groups of 256 j
        bool a0 = (kv[g].x == qc[0]) | (kv[g].y == qc[0]) | (kv[g].z == qc[0]) | (kv[g].w == qc[0]);
        bool a1 = (kv[g].x == qc[1]) | (kv[g].y == qc[1]) | (kv[g].z == qc[1]) | (kv[g].w == qc[1]);
        bool a2 = (kv[g].x == qc[2]) | (kv[g].y == qc[2]) | (kv[g].z == qc[2]) | (kv[g].w == qc[2]);
        bool a3 = (kv[g].x == qc[3]) | (kv[g].y == qc[3]) | (kv[g].z == qc[3]) | (kv[g].w == qc[3]);
        if (__ballot(a0 | a1 | a2 | a3) == 0) continue;    // usual case
        int j0 = g * 256 + lane * 4;
        #pragma unroll
        for (int i = 0; i < QPW; ++i) {            // full unroll: no runtime idx
            if (cnt[i] >= KMAX) continue;          // wave-uniform
            bool m0 = (kv[g].x == qc[i]), m1 = (kv[g].y == qc[i]);
            bool m2 = (kv[g].z == qc[i]), m3 = (kv[g].w == qc[i]);
            if (__ballot(m0 | m1 | m2 | m3) == 0) continue;
            u64 b0 = __ballot(m0), b1 = __ballot(m1);
            u64 b2 = __ballot(m2), b3 = __ballot(m3);
            int before = __popcll(b0 & lowmask) + __popcll(b1 & lowmask)
                       + __popcll(b2 & lowmask) + __popcll(b3 & lowmask);
            int pos = cnt[i] + before;
            int* op = outb + i * KMAX;
            if (m0) { if (pos < KMAX) op[pos] = j0;     ++pos; }
            if (m1) { if (pos < KMAX) op[pos] = j0 + 1; ++pos; }
            if (m2) { if (pos < KMAX) op[pos] = j0 + 2; ++pos; }
            if (m3) { if (pos < KMAX) op[pos] = j0 + 3; ++pos; }
            cnt[i] += __popcll(b0) + __popcll(b1) + __popcll(b2) + __popcll(b3);
        }
    }
    #pragma unroll
    for (int i = 0; i < QPW; ++i) {                // -1 tail fill, coalesced
        int p = cnt[i] + lane;
        if (p < KMAX) outb[i * KMAX + p] = -1;
    }
}

extern "C" void kernel_launch(void* const* d_in, const int* in_sizes, int n_in,
                              void* d_out, int out_size, void* d_ws, size_t ws_size,
                              hipStream_t stream) {
    const float* q = (const float*)d_in[0];
    const float* k = (const float*)d_in[1];
    const float* W = (const float*)d_in[2];
    int* out = (int*)d_out;
    int* codes = (int*)d_ws;                 // [2*TOK] ints (128 KB)
    int* qcodes = codes;
    int* kcodes = codes + TOK;

    codes_kernel<<<(2 * TOK) / 64, 64, 0, stream>>>(q, k, W, codes);

    find_kernel<<<TOK / QPB, 512, 0, stream>>>(qcodes, kcodes, out);
}